// Round 8
// baseline (183.593 us; speedup 1.0000x reference)
//
#include <hip/hip_runtime.h>
#include <math.h>

typedef unsigned long long ull;

#define N      512
#define DIN    256
#define LAM    0.43f
#define MAGIC  0x4D535431u
#define PAD(j) ((j) + (((j) >> 6) << 2))  // +4 words per 64 -> 2-way LDS banks

// ---------------------------------------------------------------------------
// ws word offsets (floats). All flags one-shot, compared ==MAGIC (0xAA/0 safe).
//   [4] ldready [5] t0ready [6] t0bits [7] xdready
//   [8..71] blkmax   [128..639] ae_part   +1024 lat[1024]
//   +2048 xd[262144]  +264192 ld[262144]
//   +526336 cand u64[2][3][512] (per-phase buffers, init'd pre-barrier)
//   +532480 ptab u64[2][64][64] (pairwise table, init'd pre-barrier)
//   +548864 bars u32: xbar[64] mbar[64] lbar[64] pbar[2][4][64]
// end 549568 floats ~= 2.20 MB
// ---------------------------------------------------------------------------
#define OFF_LDREADY 4
#define OFF_T0READY 5
#define OFF_T0BITS  6
#define OFF_XDREADY 7
#define OFF_BLKMAX  8
#define OFF_AEPART  128
#define OFF_LAT     1024
#define OFF_XD      2048
#define OFF_LD      (2048 + 262144)
#define OFF_CAND    526336
#define OFF_PTAB    (OFF_CAND + 6144)
#define OFF_BAR     (OFF_PTAB + 16384)

__device__ __forceinline__ unsigned ld_acq(unsigned* p) {
    return __hip_atomic_load(p, __ATOMIC_ACQUIRE, __HIP_MEMORY_SCOPE_AGENT);
}
__device__ __forceinline__ void st_rel(unsigned* p, unsigned v) {
    __hip_atomic_store(p, v, __ATOMIC_RELEASE, __HIP_MEMORY_SCOPE_AGENT);
}
__device__ __forceinline__ unsigned ld_rlx(unsigned* p) {
    return __hip_atomic_load(p, __ATOMIC_RELAXED, __HIP_MEMORY_SCOPE_AGENT);
}
__device__ __forceinline__ ull ld64_rlx(ull* p) {
    return __hip_atomic_load(p, __ATOMIC_RELAXED, __HIP_MEMORY_SCOPE_AGENT);
}
__device__ __forceinline__ void st64_rlx(ull* p, ull v) {
    __hip_atomic_store(p, v, __ATOMIC_RELAXED, __HIP_MEMORY_SCOPE_AGENT);
}
__device__ __forceinline__ void spin_magic(unsigned* p) {
    while (ld_acq(p) != MAGIC) __builtin_amdgcn_s_sleep(1);
}

// ============================================================================
// ONE kernel, 128 blocks x 256. Two parallel tracks:
//  m=0 (blocks 0..63):  pdist_x tile wb -> xbar -> Boruvka(xd)
//  m=1 (blocks 64..127): batched-8 MLP -> mbar -> ld rows -> lbar -> Boruvka(ld)
// Boruvka: regular distributed phases while nc>64 (<=3 by halving guarantee),
// then ONE pairwise-component-min scan + leader-only LDS finisher (no more
// global barriers). Epilogue on leaders; cross-track via MAGIC flags (acyclic).
// ============================================================================
__global__ __launch_bounds__(256) void mega_kernel(
    const float* __restrict__ x,
    const float* __restrict__ W1, const float* __restrict__ b1,
    const float* __restrict__ W2, const float* __restrict__ b2,
    const float* __restrict__ Wm, const float* __restrict__ bm,
    const float* __restrict__ W3, const float* __restrict__ b3,
    const float* __restrict__ W4, const float* __restrict__ b4,
    const float* __restrict__ W5, const float* __restrict__ b5,
    const float* __restrict__ latent_norm,
    float* __restrict__ wsf, float* __restrict__ out)
{
    __shared__ __align__(16) unsigned char scratch[32768]; // ptabL / As+Bs / mlp bufs
    __shared__ unsigned comp_a[512];
    __shared__ __align__(16) unsigned comp_s[544];
    __shared__ ull cval[512];                 // regular gather; reused as rowT[8][64]
    __shared__ int tgt[512];                  // regular targets; reused as cidx
    __shared__ unsigned short eu[512], ev[512];
    __shared__ float ew[512];
    __shared__ float latx[512], laty[512];
    __shared__ float latv[8][2];
    __shared__ float aered[4][8];
    __shared__ int s_arow[8];
    __shared__ unsigned lc[64];
    __shared__ int lt_[64];
    __shared__ ull rcn[64];
    __shared__ float s_red[4];
    __shared__ float s_xdm;
    __shared__ int s_ecnt, s_h;

    const int tid = threadIdx.x;
    const int blk = blockIdx.x;
    const int m   = blk >> 6;
    const int wb  = blk & 63;
    const bool leader = (wb == 0);
    const float INF = __int_as_float(0x7f800000);

    float* xd     = wsf + OFF_XD;
    float* ld     = wsf + OFF_LD;
    float* latg   = wsf + OFF_LAT;
    float* blkmax = wsf + OFF_BLKMAX;
    float* ae_g   = wsf + OFF_AEPART;
    unsigned* ldready = (unsigned*)(wsf + OFF_LDREADY);
    unsigned* t0ready = (unsigned*)(wsf + OFF_T0READY);
    unsigned* t0bits  = (unsigned*)(wsf + OFF_T0BITS);
    unsigned* xdready = (unsigned*)(wsf + OFF_XDREADY);
    ull* candm = (ull*)(wsf + OFF_CAND) + (size_t)m * 1536;   // 3 phases x 512
    ull* ptabm = (ull*)(wsf + OFF_PTAB) + (size_t)m * 4096;   // 64 x 64
    unsigned* barw = (unsigned*)(wsf + OFF_BAR);
    unsigned* xbar = barw;
    unsigned* mbar = barw + 64;
    unsigned* lbar = barw + 128;
    unsigned* pbar = barw + 192 + (size_t)m * 256;            // 4 x 64

    const float* Dm = m ? ld : xd;
    const float* Om = m ? xd : ld;

    // ---- init this block's slices of cand (24 u64) and ptab (64 u64) ----
    for (int i = tid; i < 24; i += 256) st64_rlx(&candm[(size_t)wb * 24 + i], ~0ULL);
    for (int i = tid; i < 64; i += 256) st64_rlx(&ptabm[(size_t)wb * 64 + i], ~0ULL);

    // =================== track work ===================
    if (m == 0) {
        // ---- pdist_x tile wb ----
        float (*As)[65] = (float(*)[65])scratch;
        float (*Bs)[65] = (float(*)[65])(scratch + 8320);
        const int bi = wb & 7, bj = wb >> 3;
        const int i0 = bi * 64, j0 = bj * 64;
        const int ty = tid >> 4, tx = tid & 15;

        float acc[4][4];
        #pragma unroll
        for (int i = 0; i < 4; ++i)
            #pragma unroll
            for (int j = 0; j < 4; ++j) acc[i][j] = 0.f;

        for (int kk = 0; kk < DIN; kk += 32) {
            #pragma unroll
            for (int s = tid; s < 512; s += 256) {
                int r = s >> 3, c4 = (s & 7) << 2;
                float4 va = *(const float4*)(x + (size_t)(i0 + r) * DIN + kk + c4);
                As[c4 + 0][r] = va.x; As[c4 + 1][r] = va.y;
                As[c4 + 2][r] = va.z; As[c4 + 3][r] = va.w;
                float4 vb = *(const float4*)(x + (size_t)(j0 + r) * DIN + kk + c4);
                Bs[c4 + 0][r] = vb.x; Bs[c4 + 1][r] = vb.y;
                Bs[c4 + 2][r] = vb.z; Bs[c4 + 3][r] = vb.w;
            }
            __syncthreads();
            #pragma unroll 8
            for (int k = 0; k < 32; ++k) {
                float a[4], b[4];
                #pragma unroll
                for (int i = 0; i < 4; ++i) a[i] = As[k][ty + 16 * i];
                #pragma unroll
                for (int j = 0; j < 4; ++j) b[j] = Bs[k][tx + 16 * j];
                #pragma unroll
                for (int i = 0; i < 4; ++i)
                    #pragma unroll
                    for (int j = 0; j < 4; ++j) {
                        float d = a[i] - b[j];
                        acc[i][j] = fmaf(d, d, acc[i][j]);
                    }
            }
            __syncthreads();
        }

        float lmax = 0.f;
        #pragma unroll
        for (int i = 0; i < 4; ++i)
            #pragma unroll
            for (int j = 0; j < 4; ++j) {
                float dd = sqrtf(acc[i][j]);
                int r = i0 + ty + 16 * i, c = j0 + tx + 16 * j;
                xd[(size_t)r * N + c] = dd;
                lmax = fmaxf(lmax, dd);
            }
        #pragma unroll
        for (int mm = 32; mm >= 1; mm >>= 1) lmax = fmaxf(lmax, __shfl_xor(lmax, mm, 64));
        if ((tid & 63) == 0) s_red[tid >> 6] = lmax;
        __syncthreads();
        if (tid == 0)
            blkmax[wb] = fmaxf(fmaxf(s_red[0], s_red[1]), fmaxf(s_red[2], s_red[3]));
        __syncthreads();
        if (tid == 0) st_rel(&xbar[wb], MAGIC);
        if (tid < 64) spin_magic(&xbar[tid]);
        __syncthreads();
        if (leader && tid == 0) st_rel(xdready, MAGIC);
    } else {
        // ---- batched MLP: 8 rows r0..r0+7 ----
        float* xs = (float*)scratch;          // [8][256]
        float* h1 = xs + 2048;                // [8][128]
        float* h2 = h1 + 1024;                // [8][64]
        float* h3 = h2 + 512;                 // [8][64]
        float* h4 = h3 + 512;                 // [8][128]
        const int r0 = wb << 3;

        for (int q = tid; q < 512; q += 256) {
            int rr = q >> 6, c4 = (q & 63) << 2;
            *(float4*)&xs[rr * 256 + c4] =
                *(const float4*)(x + (size_t)(r0 + rr) * DIN + c4);
        }
        __syncthreads();
        {   // L1: h1 = relu(xs @ W1 + b1)
            int c = tid & 127, rb = (tid >> 7) << 2;
            float a0 = b1[c], a1 = a0, a2 = a0, a3 = a0;
            #pragma unroll 4
            for (int k = 0; k < 256; ++k) {
                float w = W1[k * 128 + c];
                a0 = fmaf(xs[(rb + 0) * 256 + k], w, a0);
                a1 = fmaf(xs[(rb + 1) * 256 + k], w, a1);
                a2 = fmaf(xs[(rb + 2) * 256 + k], w, a2);
                a3 = fmaf(xs[(rb + 3) * 256 + k], w, a3);
            }
            h1[(rb + 0) * 128 + c] = fmaxf(a0, 0.f);
            h1[(rb + 1) * 128 + c] = fmaxf(a1, 0.f);
            h1[(rb + 2) * 128 + c] = fmaxf(a2, 0.f);
            h1[(rb + 3) * 128 + c] = fmaxf(a3, 0.f);
        }
        __syncthreads();
        {   // L2
            int c = tid & 63, rb = (tid >> 6) << 1;
            float a0 = b2[c], a1 = a0;
            #pragma unroll 4
            for (int k = 0; k < 128; ++k) {
                float w = W2[k * 64 + c];
                a0 = fmaf(h1[(rb + 0) * 128 + k], w, a0);
                a1 = fmaf(h1[(rb + 1) * 128 + k], w, a1);
            }
            h2[(rb + 0) * 64 + c] = fmaxf(a0, 0.f);
            h2[(rb + 1) * 64 + c] = fmaxf(a1, 0.f);
        }
        __syncthreads();
        if (tid < 16) {   // mid: lat
            int r = tid >> 1, c = tid & 1;
            float a = bm[c];
            #pragma unroll 4
            for (int k = 0; k < 64; ++k) a = fmaf(h2[r * 64 + k], Wm[k * 2 + c], a);
            latv[r][c] = a;
            latg[(size_t)(r0 + r) * 2 + c] = a;
        }
        __syncthreads();
        {   // L3
            int c = tid & 63, rb = (tid >> 6) << 1;
            #pragma unroll
            for (int j = 0; j < 2; ++j) {
                int r = rb + j;
                float a = b3[c] + latv[r][0] * W3[c] + latv[r][1] * W3[64 + c];
                h3[r * 64 + c] = fmaxf(a, 0.f);
            }
        }
        __syncthreads();
        {   // L4
            int c = tid & 127, rb = (tid >> 7) << 2;
            float a0 = b4[c], a1 = a0, a2 = a0, a3 = a0;
            #pragma unroll 4
            for (int k = 0; k < 64; ++k) {
                float w = W4[k * 128 + c];
                a0 = fmaf(h3[(rb + 0) * 64 + k], w, a0);
                a1 = fmaf(h3[(rb + 1) * 64 + k], w, a1);
                a2 = fmaf(h3[(rb + 2) * 64 + k], w, a2);
                a3 = fmaf(h3[(rb + 3) * 64 + k], w, a3);
            }
            h4[(rb + 0) * 128 + c] = fmaxf(a0, 0.f);
            h4[(rb + 1) * 128 + c] = fmaxf(a1, 0.f);
            h4[(rb + 2) * 128 + c] = fmaxf(a2, 0.f);
            h4[(rb + 3) * 128 + c] = fmaxf(a3, 0.f);
        }
        __syncthreads();
        {   // L5 + AE partials
            int c = tid;
            float a[8];
            #pragma unroll
            for (int r = 0; r < 8; ++r) a[r] = b5[c];
            #pragma unroll 2
            for (int k = 0; k < 128; ++k) {
                float w = W5[k * 256 + c];
                #pragma unroll
                for (int r = 0; r < 8; ++r) a[r] = fmaf(h4[r * 128 + k], w, a[r]);
            }
            #pragma unroll
            for (int r = 0; r < 8; ++r) {
                float d = xs[r * 256 + c] - a[r];
                float v = d * d;
                #pragma unroll
                for (int mm = 1; mm < 64; mm <<= 1) v += __shfl_xor(v, mm, 64);
                if ((tid & 63) == 0) aered[tid >> 6][r] = v;
            }
            __syncthreads();
            if (tid < 8)
                ae_g[r0 + tid] = aered[0][tid] + aered[1][tid]
                               + aered[2][tid] + aered[3][tid];
        }
        __syncthreads();
        if (tid == 0) st_rel(&mbar[wb], MAGIC);
        if (tid < 64) spin_magic(&mbar[tid]);
        __syncthreads();
        // ---- ld rows (needs ALL lat) ----
        for (int i = tid; i < 512; i += 256) {
            float2 v = *(const float2*)(latg + 2 * i);
            latx[i] = v.x; laty[i] = v.y;
        }
        __syncthreads();
        for (int q = tid; q < 1024; q += 256) {
            int rr = r0 + (q >> 7);
            int j  = (q & 127) << 2;
            float xi = latx[rr], yi = laty[rr];
            float dx0 = xi - latx[j + 0], dy0 = yi - laty[j + 0];
            float dx1 = xi - latx[j + 1], dy1 = yi - laty[j + 1];
            float dx2 = xi - latx[j + 2], dy2 = yi - laty[j + 2];
            float dx3 = xi - latx[j + 3], dy3 = yi - laty[j + 3];
            float4 o;
            o.x = sqrtf(fmaf(dx0, dx0, dy0 * dy0));
            o.y = sqrtf(fmaf(dx1, dx1, dy1 * dy1));
            o.z = sqrtf(fmaf(dx2, dx2, dy2 * dy2));
            o.w = sqrtf(fmaf(dx3, dx3, dy3 * dy3));
            *(float4*)(ld + (size_t)rr * N + j) = o;
        }
        __syncthreads();
        if (tid == 0) st_rel(&lbar[wb], MAGIC);
        if (tid < 64) spin_magic(&lbar[tid]);
        __syncthreads();
        if (leader && tid == 0) st_rel(ldready, MAGIC);
    }

    // =================== Boruvka ===================
    for (int i = tid; i < 512; i += 256) {
        comp_a[i] = (unsigned)i;
        comp_s[PAD(i)] = (unsigned)i;
    }
    if (tid == 0) s_ecnt = 0;
    __syncthreads();

    int nc = 512, p = 0;
    while (nc > 64) {                       // <=3 regular phases (halving)
        ull* cand = candm + (size_t)p * 512;
        {   // scan: 8 rows/block, 32 thr/row, 16 cols/thr
            const int r  = (wb << 3) + (tid >> 5);
            const int c0 = (tid & 31) << 4;
            const unsigned cv = comp_s[PAD(r)];
            const float4* rp = (const float4*)(Dm + (size_t)r * N + c0);
            ull bk = ~0ULL;
            #pragma unroll
            for (int c = 0; c < 4; ++c) {
                float4 f = rp[c];
                int jb = c0 + 4 * c;
                int4 cc = *(const int4*)&comp_s[PAD(jb)];
                ull k;
                k = ((ull)__float_as_uint(f.x) << 18) | ((ull)r << 9) | (unsigned)(jb + 0);
                if ((unsigned)cc.x != cv && k < bk) bk = k;
                k = ((ull)__float_as_uint(f.y) << 18) | ((ull)r << 9) | (unsigned)(jb + 1);
                if ((unsigned)cc.y != cv && k < bk) bk = k;
                k = ((ull)__float_as_uint(f.z) << 18) | ((ull)r << 9) | (unsigned)(jb + 2);
                if ((unsigned)cc.z != cv && k < bk) bk = k;
                k = ((ull)__float_as_uint(f.w) << 18) | ((ull)r << 9) | (unsigned)(jb + 3);
                if ((unsigned)cc.w != cv && k < bk) bk = k;
            }
            #pragma unroll
            for (int mm = 1; mm <= 16; mm <<= 1) {
                ull o = __shfl_xor(bk, mm, 64);
                if (o < bk) bk = o;
            }
            if ((tid & 31) == 0 && bk != ~0ULL) atomicMin(&cand[cv], bk);
        }
        __syncthreads();
        if (tid == 0) st_rel(&pbar[p * 64 + wb], MAGIC);
        if (tid < 64) spin_magic(&pbar[p * 64 + tid]);
        __syncthreads();

        // gather + hook + contract (redundant per block)
        for (int i = tid; i < 512; i += 256) cval[i] = ld64_rlx(&cand[i]);
        __syncthreads();
        for (int i = tid; i < 512; i += 256) {
            int t = -1;
            if (comp_a[i] == (unsigned)i && cval[i] != ~0ULL)
                t = (int)comp_a[cval[i] & 511];
            tgt[i] = t;
        }
        __syncthreads();
        for (int i = tid; i < 512; i += 256) {
            int s = tgt[i];
            if (s >= 0 && !(tgt[s] == i && i > s)) {
                comp_a[i] = (unsigned)s;
                int e = atomicAdd(&s_ecnt, 1);
                ull c = cval[i];
                eu[e] = (unsigned short)((c >> 9) & 511);
                ev[e] = (unsigned short)(c & 511);
                ew[e] = __uint_as_float((unsigned)(c >> 18));
            }
        }
        __syncthreads();
        for (int dd = 0; dd < 9; ++dd) {
            unsigned a = comp_a[comp_a[tid]];
            unsigned b = comp_a[comp_a[tid + 256]];
            __syncthreads();
            comp_a[tid] = a; comp_a[tid + 256] = b;
            __syncthreads();
        }
        for (int i = tid; i < 512; i += 256) comp_s[PAD(i)] = comp_a[i];
        nc = 512 - s_ecnt;
        __syncthreads();
        ++p;
    }

    if (nc > 1) {
        // ---- compact root ids (cidx into tgt[]) via wave-0 prefix ----
        if (tid < 64) {
            int base = tid << 3;
            unsigned f[8]; unsigned cnt = 0;
            #pragma unroll
            for (int k = 0; k < 8; ++k) {
                f[k] = (comp_a[base + k] == (unsigned)(base + k)) ? 1u : 0u;
                cnt += f[k];
            }
            unsigned s = cnt;
            #pragma unroll
            for (int o = 1; o < 64; o <<= 1) {
                unsigned v = __shfl_up(s, o, 64);
                if (tid >= o) s += v;
            }
            int run = (int)(s - cnt);
            #pragma unroll
            for (int k = 0; k < 8; ++k)
                if (f[k]) tgt[base + k] = run++;
        }
        __syncthreads();

        // ---- pairwise scan into LDS rowT then global ptab ----
        ull* rowT = cval;                       // [8][64]
        for (int i = tid; i < 512; i += 256) rowT[i] = ~0ULL;
        if (tid < 8) s_arow[tid] = tgt[comp_a[(wb << 3) + tid]];
        __syncthreads();
        {
            const int rl = tid >> 5;
            const int r  = (wb << 3) + rl;
            const int c0 = (tid & 31) << 4;
            const int av = tgt[comp_a[r]];
            const float4* rp = (const float4*)(Dm + (size_t)r * N + c0);
            #pragma unroll
            for (int c = 0; c < 4; ++c) {
                float4 f = rp[c];
                int jb = c0 + 4 * c;
                const float w4[4] = {f.x, f.y, f.z, f.w};
                #pragma unroll
                for (int t4 = 0; t4 < 4; ++t4) {
                    int j = jb + t4;
                    int b = tgt[comp_a[j]];
                    if (b != av) {
                        ull k = ((ull)__float_as_uint(w4[t4]) << 18)
                              | ((ull)r << 9) | (unsigned)j;
                        atomicMin(&rowT[rl * 64 + b], k);
                    }
                }
            }
        }
        __syncthreads();
        for (int i = tid; i < 512; i += 256) {
            ull v = rowT[i];
            if (v != ~0ULL)
                atomicMin(&ptabm[(size_t)s_arow[i >> 6] * 64 + (i & 63)], v);
        }
        __syncthreads();
        if (tid == 0) st_rel(&pbar[p * 64 + wb], MAGIC);
        if (!leader) return;
        if (tid < 64) spin_magic(&pbar[p * 64 + tid]);
        __syncthreads();

        // ---- leader-only LDS finisher on the nc-node dense comp graph ----
        ull* ptabL = (ull*)scratch;             // 64x64
        for (int i = tid; i < 4096; i += 256) ptabL[i] = ld64_rlx(&ptabm[i]);
        if (tid < 64) lc[tid] = (unsigned)tid;
        __syncthreads();
        int lnc = nc;
        for (int round = 0; round < 6 && lnc > 1; ++round) {
            if (tid < 64) rcn[tid] = ~0ULL;
            __syncthreads();
            if (tid < nc) {
                unsigned la = lc[tid];
                ull bk = ~0ULL;
                for (int b = 0; b < nc; ++b) {
                    if (lc[b] != la) {
                        ull k = ptabL[tid * 64 + b];
                        if (k < bk) bk = k;
                    }
                }
                if (bk != ~0ULL) atomicMin(&rcn[la], bk);
            }
            __syncthreads();
            if (tid < 64) {
                int t = -1;
                if (tid < nc && lc[tid] == (unsigned)tid && rcn[tid] != ~0ULL) {
                    int jv = (int)(rcn[tid] & 511);
                    t = (int)lc[tgt[comp_a[jv]]];
                }
                lt_[tid] = t;
            }
            if (tid == 0) s_h = 0;
            __syncthreads();
            if (tid < 64) {
                int t = lt_[tid];
                if (t >= 0 && !(lt_[t] == tid && tid > t)) {
                    lc[tid] = (unsigned)t;
                    int e = atomicAdd(&s_ecnt, 1);
                    atomicAdd(&s_h, 1);
                    ull k = rcn[tid];
                    eu[e] = (unsigned short)((k >> 9) & 511);
                    ev[e] = (unsigned short)(k & 511);
                    ew[e] = __uint_as_float((unsigned)(k >> 18));
                }
            }
            __syncthreads();
            for (int dd = 0; dd < 6; ++dd) {
                unsigned v = (tid < 64) ? lc[lc[tid]] : 0u;
                __syncthreads();
                if (tid < 64) lc[tid] = v;
                __syncthreads();
            }
            lnc -= s_h;
            __syncthreads();
        }
    } else {
        if (!leader) return;
    }

    // =================== epilogue (leaders only) ===================
    if (m == 1) { if (tid == 0) spin_magic(xdready); __syncthreads(); }
    else        { if (tid == 0) spin_magic(ldready); __syncthreads(); }

    if (tid < 64) {
        float mx = blkmax[tid];
        #pragma unroll
        for (int mm = 32; mm >= 1; mm >>= 1) mx = fmaxf(mx, __shfl_xor(mx, mm, 64));
        if (tid == 0) s_xdm = mx;
    }
    __syncthreads();
    const float xdm = s_xdm;
    const float lnv = latent_norm[0];
    const float sD = (m == 0) ? 1.f / xdm : 1.f / lnv;
    const float sO = (m == 0) ? 1.f / lnv : 1.f / xdm;

    const int ne = s_ecnt;                  // 511
    float acc = 0.f;
    for (int i = tid; i < ne; i += 256) {
        float de = ew[i];
        float oe = Om[(size_t)eu[i] * N + ev[i]];
        float c = sD * de - sO * oe;
        acc = fmaf(c, c, acc);
    }
    #pragma unroll
    for (int mm = 32; mm >= 1; mm >>= 1) acc += __shfl_xor(acc, mm, 64);
    if ((tid & 63) == 0) s_red[tid >> 6] = acc;
    __syncthreads();

    if (m == 0) {
        if (tid == 0) {
            float t0 = s_red[0] + s_red[1] + s_red[2] + s_red[3];
            __hip_atomic_store(t0bits, __float_as_uint(t0), __ATOMIC_RELAXED,
                               __HIP_MEMORY_SCOPE_AGENT);
            st_rel(t0ready, MAGIC);
        }
    } else {
        float t1 = 0.f;
        if (tid == 0) t1 = s_red[0] + s_red[1] + s_red[2] + s_red[3];
        __syncthreads();                    // s_red reused
        float a = ae_g[tid] + ae_g[tid + 256];
        #pragma unroll
        for (int mm = 32; mm >= 1; mm >>= 1) a += __shfl_xor(a, mm, 64);
        if ((tid & 63) == 0) s_red[tid >> 6] = a;
        __syncthreads();
        if (tid == 0) {
            float ae = s_red[0] + s_red[1] + s_red[2] + s_red[3];
            spin_magic(t0ready);
            float t0 = __uint_as_float(ld_rlx(t0bits));
            out[0] = ae * (1.f / (float)(N * DIN))
                   + (LAM * (t0 + t1)) * (1.f / (float)N);
        }
    }
}

extern "C" void kernel_launch(void* const* d_in, const int* in_sizes, int n_in,
                              void* d_out, int out_size, void* d_ws, size_t ws_size,
                              hipStream_t stream) {
    (void)in_sizes; (void)n_in; (void)out_size; (void)ws_size;
    const float* x   = (const float*)d_in[0];
    // d_in[1] = label (unused)
    const float* W1  = (const float*)d_in[2];
    const float* b1  = (const float*)d_in[3];
    const float* W2  = (const float*)d_in[4];
    const float* b2  = (const float*)d_in[5];
    const float* Wm  = (const float*)d_in[6];
    const float* bm  = (const float*)d_in[7];
    const float* W3  = (const float*)d_in[8];
    const float* b3  = (const float*)d_in[9];
    const float* W4  = (const float*)d_in[10];
    const float* b4  = (const float*)d_in[11];
    const float* W5  = (const float*)d_in[12];
    const float* b5  = (const float*)d_in[13];
    const float* latent_norm = (const float*)d_in[14];

    mega_kernel<<<128, 256, 0, stream>>>(
        x, W1, b1, W2, b2, Wm, bm, W3, b3, W4, b4, W5, b5,
        latent_norm, (float*)d_ws, (float*)d_out);
}